// Round 1
// baseline (849.093 us; speedup 1.0000x reference)
//
#include <hip/hip_runtime.h>
#include <hip/hip_bf16.h>
#include <math.h>

typedef __bf16 bf16_t;
typedef bf16_t bf16x8 __attribute__((ext_vector_type(8)));
typedef bf16_t bf16x4 __attribute__((ext_vector_type(4)));
typedef float f32x4 __attribute__((ext_vector_type(4)));

#define DEVINL __device__ __forceinline__

DEVINL float wave_reduce_sum(float v) {
#pragma unroll
  for (int o = 32; o > 0; o >>= 1) v += __shfl_down(v, o);
  return v;
}
DEVINL float wave_reduce_max(float v) {
#pragma unroll
  for (int o = 32; o > 0; o >>= 1) v = fmaxf(v, __shfl_down(v, o));
  return v;
}
// 256-thread block reductions; red[] >= 4 floats. Leading sync protects reuse.
DEVINL float block_reduce_sum256(float v, float* red) {
  int tid = threadIdx.x;
  __syncthreads();
  v = wave_reduce_sum(v);
  if ((tid & 63) == 0) red[tid >> 6] = v;
  __syncthreads();
  return red[0] + red[1] + red[2] + red[3];
}
DEVINL float block_reduce_max256(float v, float* red) {
  int tid = threadIdx.x;
  __syncthreads();
  v = wave_reduce_max(v);
  if ((tid & 63) == 0) red[tid >> 6] = v;
  __syncthreads();
  return fmaxf(fmaxf(red[0], red[1]), fmaxf(red[2], red[3]));
}

// ---------------- LayerNorm (one block per row, 256 threads) ----------------
template <int CPT, bool BF16OUT>
__global__ __launch_bounds__(256) void k_ln(const float* __restrict__ x,
                                            const float* __restrict__ g,
                                            const float* __restrict__ b,
                                            void* __restrict__ out) {
  constexpr int COLS = CPT * 256;
  __shared__ float red[8];
  const size_t row = blockIdx.x;
  const float* xr = x + row * COLS;
  const int c0 = threadIdx.x * CPT;
  float v[CPT];
#pragma unroll
  for (int j = 0; j < CPT; j++) v[j] = xr[c0 + j];
  float s = 0;
#pragma unroll
  for (int j = 0; j < CPT; j++) s += v[j];
  const float mu = block_reduce_sum256(s, red) * (1.0f / COLS);
  float q = 0;
#pragma unroll
  for (int j = 0; j < CPT; j++) { float d = v[j] - mu; q += d * d; }
  const float var = block_reduce_sum256(q, red) * (1.0f / COLS);
  const float rs = rsqrtf(var + 1e-5f);
  if constexpr (BF16OUT) {
    bf16x4 o;
#pragma unroll
    for (int j = 0; j < CPT; j++)
      o[j] = (bf16_t)((v[j] - mu) * rs * g[c0 + j] + b[c0 + j]);
    *(bf16x4*)((bf16_t*)out + row * COLS + c0) = o;
  } else {
#pragma unroll
    for (int j = 0; j < CPT; j++)
      ((float*)out)[row * COLS + c0 + j] = (v[j] - mu) * rs * g[c0 + j] + b[c0 + j];
  }
}

// ------------- transpose + cast fp32[K][N] -> bf16[N][K] ----------------
__global__ __launch_bounds__(256) void k_tcast(const float* __restrict__ src,
                                               bf16_t* __restrict__ dst, int K, int N) {
  __shared__ float t[32][33];
  const int n0 = blockIdx.x * 32, k0 = blockIdx.y * 32;
  const int tx = threadIdx.x, ty = threadIdx.y;  // 32 x 8
#pragma unroll
  for (int i = 0; i < 32; i += 8)
    t[ty + i][tx] = src[(size_t)(k0 + ty + i) * N + n0 + tx];
  __syncthreads();
#pragma unroll
  for (int i = 0; i < 32; i += 8)
    dst[(size_t)(n0 + ty + i) * K + k0 + tx] = (bf16_t)t[tx][ty + i];
}

// ------ fold gat_wd [512,512] with att_d [8,64] -> wd_att [512,8] ------
__global__ __launch_bounds__(256) void k_fold_wd(const float* __restrict__ gat_wd,
                                                 const float* __restrict__ att_d,
                                                 float* __restrict__ wd_att) {
  const int k = blockIdx.x * 256 + threadIdx.x;  // grid 2 -> k in [0,512)
#pragma unroll
  for (int h = 0; h < 8; h++) {
    float s = 0;
    for (int c = 0; c < 64; c++)
      s += gat_wd[(size_t)k * 512 + h * 64 + c] * att_d[h * 64 + c];
    wd_att[k * 8 + h] = s;
  }
}

// ---------------- MFMA bf16 GEMM, C = A[M,K] * Bt[N,K]^T ----------------
// 128x128 tile, BK=64, 4 waves (2x2), global_load_lds staging (m97 structure).
// EPI: 0 = bias+relu -> bf16 ; 1 = bias -> bf16 ; 2 = no bias -> bf16 ;
//      3 = bias -> fp32, strided output row r -> r + (r>>10) + 1 (of-layout)
template <int N, int K, int EPI>
__global__ __launch_bounds__(256, 2) void gemm_bt(const bf16_t* __restrict__ A,
                                                  const bf16_t* __restrict__ Bt,
                                                  const float* __restrict__ bias,
                                                  void* __restrict__ Cout) {
  __shared__ bf16_t As[128 * 64];
  __shared__ bf16_t Bs[128 * 64];
  const int tid = threadIdx.x;
  const int lane = tid & 63;
  const int wid = tid >> 6;
  const int wm = wid >> 1, wn = wid & 1;
  const size_t arow0 = (size_t)blockIdx.x * 128;
  const int bcol0 = blockIdx.y * 128;

  f32x4 acc[4][4] = {};
  const int kTiles = K / 64;
  for (int kt = 0; kt < kTiles; ++kt) {
    const int k0 = kt * 64;
#pragma unroll
    for (int i = 0; i < 4; ++i) {
      const int c = i * 256 + tid;
      const int r = c >> 3, kc = (c & 7) * 8;
      const bf16_t* ga = A + (arow0 + r) * K + k0 + kc;
      __builtin_amdgcn_global_load_lds(
          (const __attribute__((address_space(1))) void*)ga,
          (__attribute__((address_space(3))) void*)(As + c * 8), 16, 0, 0);
      const bf16_t* gb = Bt + ((size_t)bcol0 + r) * K + k0 + kc;
      __builtin_amdgcn_global_load_lds(
          (const __attribute__((address_space(1))) void*)gb,
          (__attribute__((address_space(3))) void*)(Bs + c * 8), 16, 0, 0);
    }
    __syncthreads();
#pragma unroll
    for (int kk = 0; kk < 2; ++kk) {
      bf16x8 af[4], bfr[4];
      const int kofs = kk * 32 + (lane >> 4) * 8;
#pragma unroll
      for (int m = 0; m < 4; ++m)
        af[m] = *(const bf16x8*)(As + (wm * 64 + m * 16 + (lane & 15)) * 64 + kofs);
#pragma unroll
      for (int n = 0; n < 4; ++n)
        bfr[n] = *(const bf16x8*)(Bs + (wn * 64 + n * 16 + (lane & 15)) * 64 + kofs);
#pragma unroll
      for (int m = 0; m < 4; ++m)
#pragma unroll
        for (int n = 0; n < 4; ++n)
          acc[m][n] = __builtin_amdgcn_mfma_f32_16x16x32_bf16(af[m], bfr[n], acc[m][n], 0, 0, 0);
    }
    __syncthreads();
  }
  // epilogue: D lane mapping col = lane&15, row = (lane>>4)*4 + j
  const int lr = (lane >> 4) * 4;
  const int lc = lane & 15;
#pragma unroll
  for (int n = 0; n < 4; ++n) {
    const int col = bcol0 + wn * 64 + n * 16 + lc;
    const float bv = (EPI == 2) ? 0.0f : bias[col];
#pragma unroll
    for (int m = 0; m < 4; ++m) {
#pragma unroll
      for (int j = 0; j < 4; ++j) {
        const size_t row = arow0 + wm * 64 + m * 16 + lr + j;
        float v = acc[m][n][j] + bv;
        if constexpr (EPI == 0) v = v > 0.0f ? v : 0.0f;
        if constexpr (EPI == 3) {
          const size_t orow = row + (row >> 10) + 1;
          ((float*)Cout)[orow * (size_t)N + col] = v;
        } else {
          ((bf16_t*)Cout)[row * (size_t)N + col] = (bf16_t)v;
        }
      }
    }
  }
}

// ---------------- bipartite GAT attention, one block per (graph b, head h) ----
// graph b entries: its 1024 fine nodes, plus (b>=1) one extra entry from fine
// node b (self-loop); for b==0 the masked edge (0,0) and the self-loop cancel.
__global__ __launch_bounds__(256) void k_attn(const bf16_t* __restrict__ xs,
                                              const float* __restrict__ xg,
                                              const float* __restrict__ wd_att,
                                              const float* __restrict__ att_s,
                                              float* __restrict__ agg) {
  const int b = blockIdx.x >> 3, h = blockIdx.x & 7;
  const int tid = threadIdx.x;
  __shared__ float sl[1024];
  __shared__ float part[256];
  __shared__ float red[8];
  __shared__ float s_att[64];
  __shared__ float s_sc[4];
  if (tid < 64) s_att[tid] = att_s[h * 64 + tid];
  float pa = 0;
#pragma unroll
  for (int kk = 0; kk < 2; kk++) {
    const int k = tid + kk * 256;
    pa += xg[b * 512 + k] * wd_att[k * 8 + h];
  }
  const float a_d = block_reduce_sum256(pa, red);  // syncs also publish s_att
  const bf16_t* xsb = xs + ((size_t)b * 1024) * 512 + h * 64;
#pragma unroll
  for (int j = 0; j < 4; j++) {
    const int i = tid + j * 256;
    const bf16_t* xr = xsb + (size_t)i * 512;
    float s = 0;
#pragma unroll
    for (int c = 0; c < 64; c += 8) {
      bf16x8 v = *(const bf16x8*)(xr + c);
#pragma unroll
      for (int u = 0; u < 8; u++) s += (float)v[u] * s_att[c + u];
    }
    const float lg = s + a_d;
    sl[i] = lg > 0.0f ? lg : 0.2f * lg;
  }
  if (tid == 0) {
    float self_lg = -INFINITY;
    if (b != 0) {
      const bf16_t* xr = xs + (size_t)b * 512 + h * 64;
      float s = 0;
      for (int c = 0; c < 64; c++) s += (float)xr[c] * s_att[c];
      const float lg = s + a_d;
      self_lg = lg > 0.0f ? lg : 0.2f * lg;
    }
    s_sc[0] = self_lg;
  }
  __syncthreads();
  float mx = -1e30f;
#pragma unroll
  for (int j = 0; j < 4; j++) mx = fmaxf(mx, sl[tid + j * 256]);
  mx = block_reduce_max256(mx, red);
  const float m = fmaxf(mx, s_sc[0]);
  float ps = 0;
#pragma unroll
  for (int j = 0; j < 4; j++) {
    const int i = tid + j * 256;
    const float e = __expf(sl[i] - m);
    sl[i] = e;
    ps += e;
  }
  if (tid == 0) s_sc[1] = __expf(s_sc[0] - m);  // exp(-inf)=0 for b==0
  const float dsum = block_reduce_sum256(ps, red);
  const float e_self = s_sc[1];
  const float inv = 1.0f / (dsum + e_self);
  const int c = tid & 63, grp = tid >> 6;
  float acc = 0;
  const bf16_t* xcol = xs + ((size_t)b * 1024) * 512 + h * 64 + c;
  for (int i = grp * 256; i < grp * 256 + 256; i++)
    acc += sl[i] * (float)xcol[(size_t)i * 512];
  if (grp == 0) acc += e_self * (float)xs[(size_t)b * 512 + h * 64 + c];
  part[tid] = acc;
  __syncthreads();
  if (tid < 64) {
    const float t = part[tid] + part[tid + 64] + part[tid + 128] + part[tid + 192];
    agg[(size_t)b * 512 + h * 64 + tid] = t * inv;
  }
}

// -------- og: out[b,0,:] = (agg + gat_bias + xg) @ gp_w + gp_b --------
__global__ __launch_bounds__(256) void k_og(const float* __restrict__ agg,
                                            const float* __restrict__ gat_bias,
                                            const float* __restrict__ xg,
                                            const float* __restrict__ gp_w,
                                            const float* __restrict__ gp_b,
                                            float* __restrict__ out) {
  __shared__ float xv[512];
  const int b = blockIdx.y;
  const int c = blockIdx.x * 256 + threadIdx.x;
  for (int k = threadIdx.x; k < 512; k += 256)
    xv[k] = agg[b * 512 + k] + gat_bias[k] + xg[b * 512 + k];
  __syncthreads();
  float acc = gp_b[c];
#pragma unroll 8
  for (int k = 0; k < 512; k++) acc += xv[k] * gp_w[(size_t)k * 2048 + c];
  out[(size_t)b * 1025 * 2048 + c] = acc;
}

extern "C" void kernel_launch(void* const* d_in, const int* in_sizes, int n_in,
                              void* d_out, int out_size, void* d_ws, size_t ws_size,
                              hipStream_t stream) {
  const float* x_fine   = (const float*)d_in[0];
  const float* x_global = (const float*)d_in[1];
  // d_in[2]: edge_index — structure is static (i -> i/1024), not needed
  const float* nf_g  = (const float*)d_in[3];
  const float* nf_b  = (const float*)d_in[4];
  const float* ip_w1 = (const float*)d_in[5];
  const float* ip_b1 = (const float*)d_in[6];
  const float* ip_w2 = (const float*)d_in[7];
  const float* ip_b2 = (const float*)d_in[8];
  const float* ng_g  = (const float*)d_in[9];
  const float* ng_b  = (const float*)d_in[10];
  const float* gat_ws   = (const float*)d_in[11];
  const float* gat_wd   = (const float*)d_in[12];
  const float* att_s    = (const float*)d_in[13];
  const float* att_d    = (const float*)d_in[14];
  const float* gat_bias = (const float*)d_in[15];
  const float* gp_w = (const float*)d_in[16];
  const float* gp_b = (const float*)d_in[17];
  const float* fp_w = (const float*)d_in[18];
  const float* fp_b = (const float*)d_in[19];
  float* out = (float*)d_out;

  char* ws = (char*)d_ws;
  bf16_t* xf_ln = (bf16_t*)ws;                      // 128 MiB [65536,1024], reused as xf
  bf16_t* hbuf  = (bf16_t*)(ws + 134217728ULL);     // 128 MiB [65536,1024], reused as xs
  char* sm = ws + 268435456ULL;
  bf16_t* w1t = (bf16_t*)sm;                        // [1024,1024] 2 MiB
  bf16_t* w2t = (bf16_t*)(sm + 2097152ULL);         // [512,1024] 1 MiB
  bf16_t* wst = (bf16_t*)(sm + 3145728ULL);         // [512,512] 0.5 MiB
  bf16_t* fpt = (bf16_t*)(sm + 3670016ULL);         // [2048,512] 2 MiB
  float*  xg  = (float*)(sm + 5767168ULL);          // [64,512]
  float*  wd_att = (float*)(sm + 5898240ULL);       // [512,8]
  float*  aggp   = (float*)(sm + 5914624ULL);       // [64,512]
  bf16_t* xf  = xf_ln;   // [65536,512] after GEMM2 (xf_ln dead)
  bf16_t* xsb = hbuf;    // [65536,512] after GEMM3 (h dead)

  // weight prep
  k_tcast<<<dim3(32, 32), dim3(32, 8), 0, stream>>>(ip_w1, w1t, 1024, 1024);
  k_tcast<<<dim3(16, 32), dim3(32, 8), 0, stream>>>(ip_w2, w2t, 1024, 512);
  k_tcast<<<dim3(16, 16), dim3(32, 8), 0, stream>>>(gat_ws, wst, 512, 512);
  k_tcast<<<dim3(64, 16), dim3(32, 8), 0, stream>>>(fp_w, fpt, 512, 2048);
  k_fold_wd<<<2, 256, 0, stream>>>(gat_wd, att_d, wd_att);

  // norms
  k_ln<4, true><<<65536, 256, 0, stream>>>(x_fine, nf_g, nf_b, xf_ln);
  k_ln<2, false><<<64, 256, 0, stream>>>(x_global, ng_g, ng_b, xg);

  // MLP + GAT source projection
  gemm_bt<1024, 1024, 0><<<dim3(512, 8), 256, 0, stream>>>(xf_ln, w1t, ip_b1, hbuf);
  gemm_bt<512, 1024, 1><<<dim3(512, 4), 256, 0, stream>>>(hbuf, w2t, ip_b2, xf);
  gemm_bt<512, 512, 2><<<dim3(512, 4), 256, 0, stream>>>(xf, wst, nullptr, xsb);

  // attention + global head
  k_attn<<<512, 256, 0, stream>>>(xsb, xg, wd_att, att_s, aggp);
  k_og<<<dim3(8, 64), 256, 0, stream>>>(aggp, gat_bias, xg, gp_w, gp_b, out);

  // fine projection straight into strided output rows
  gemm_bt<2048, 512, 3><<<dim3(512, 16), 256, 0, stream>>>(xf, fpt, fp_b, out);
}